// Round 6
// baseline (3577.983 us; speedup 1.0000x reference)
//
#include <hip/hip_runtime.h>
#include <hip/hip_bf16.h>

#define NNODES 100000
#define HIDC 256
#define NFEAT 9
#define VOCABS 128
#define BFD 128        // bases output dim
#define NCOMB 96       // heads*bases*aggs
#define NGR 5000
#define LAYERSN 4
#define EPSV 1e-5f
#define NPB 8          // nodes per block in node GEMM

typedef __hip_bfloat16 bf16;

__device__ __forceinline__ float b2f(bf16 v) { return __bfloat162float(v); }
__device__ __forceinline__ bf16 f2b(float v) { return __float2bfloat16(v); }

// typed load/store helpers (fp32 or bf16 backing)
__device__ __forceinline__ float ldf(const float* p) { return *p; }
__device__ __forceinline__ float ldf(const bf16* p) { return b2f(*p); }
__device__ __forceinline__ void stf(float* p, float v) { *p = v; }
__device__ __forceinline__ void stf(bf16* p, float v) { *p = f2b(v); }

// 0. sentinel: encode ws_size(MB) into output if workspace too small
__global__ __launch_bounds__(256) void k_sentinel(float* out, int n, float val) {
    int i = blockIdx.x * 256 + threadIdx.x;
    if (i < n) out[i] = val;
}

// 1. AtomEncoder: h[n,c] = sum_f emb[f, x[n,f], c]
template <typename TH>
__global__ __launch_bounds__(256) void k_atom(const int* __restrict__ x,
                                              const float* __restrict__ emb,
                                              TH* __restrict__ h) {
    int n = blockIdx.x;
    __shared__ int xs[NFEAT];
    if (threadIdx.x < NFEAT) xs[threadIdx.x] = x[n * NFEAT + threadIdx.x];
    __syncthreads();
    int c = threadIdx.x;
    float acc = 0.f;
#pragma unroll
    for (int f = 0; f < NFEAT; ++f)
        acc += emb[(f * VOCABS + xs[f]) * HIDC + c];
    stf(&h[(size_t)n * HIDC + c], acc);
}

// 2a. histogram of dst
__global__ __launch_bounds__(256) void k_hist(const int* __restrict__ dst,
                                              int* __restrict__ counts, int E) {
    int e = blockIdx.x * 256 + threadIdx.x;
    if (e < E) atomicAdd(&counts[dst[e]], 1);
}

// 2b. exclusive scan counts -> rowptr (single block, chunked)
__global__ __launch_bounds__(256) void k_scan(const int* __restrict__ counts,
                                              int* __restrict__ rowptr, int n) {
    __shared__ int buf[256];
    __shared__ int off;
    int t = threadIdx.x;
    if (t == 0) { off = 0; rowptr[0] = 0; }
    __syncthreads();
    for (int base = 0; base < n; base += 256) {
        int v = (base + t < n) ? counts[base + t] : 0;
        buf[t] = v;
        __syncthreads();
        for (int s = 1; s < 256; s <<= 1) {
            int x2 = (t >= s) ? buf[t - s] : 0;
            __syncthreads();
            buf[t] += x2;
            __syncthreads();
        }
        if (base + t < n) rowptr[base + t + 1] = off + buf[t];
        __syncthreads();
        if (t == 0) off += buf[255];
        __syncthreads();
    }
}

// 2c. cursor = rowptr[0..N-1]
__global__ __launch_bounds__(256) void k_copy(const int* __restrict__ rowptr,
                                              int* __restrict__ cursor, int n) {
    int i = blockIdx.x * 256 + threadIdx.x;
    if (i < n) cursor[i] = rowptr[i];
}

// 2d. scatter src into CSR slots
__global__ __launch_bounds__(256) void k_scatter(const int* __restrict__ src,
                                                 const int* __restrict__ dst,
                                                 int* __restrict__ cursor,
                                                 int* __restrict__ csr, int E) {
    int e = blockIdx.x * 256 + threadIdx.x;
    if (e >= E) return;
    int pos = atomicAdd(&cursor[dst[e]], 1);
    csr[pos] = src[e];
}

// 3. node GEMM: bases(bf16) = h@Wb, wco = h@Wc + cb. 8 nodes/block.
template <typename TH, typename TW>
__global__ __launch_bounds__(256) void k_gemm_bw(const TH* __restrict__ h,
                                                 const float* __restrict__ Wb,
                                                 const float* __restrict__ Wc,
                                                 const float* __restrict__ cb,
                                                 bf16* __restrict__ bases,
                                                 TW* __restrict__ wco) {
    __shared__ float hs[NPB][HIDC];
    size_t n0 = (size_t)blockIdx.x * NPB;
    for (int i = threadIdx.x; i < NPB * HIDC; i += 256)
        ((float*)hs)[i] = ldf(&h[n0 * HIDC + i]);
    __syncthreads();
    int t = threadIdx.x;
    float acc[NPB];
#pragma unroll
    for (int i = 0; i < NPB; ++i) acc[i] = 0.f;
    if (t < BFD) {
        for (int k = 0; k < HIDC; ++k) {
            float w = Wb[k * BFD + t];
#pragma unroll
            for (int i = 0; i < NPB; ++i) acc[i] += hs[i][k] * w;
        }
#pragma unroll
        for (int i = 0; i < NPB; ++i) bases[(n0 + i) * BFD + t] = f2b(acc[i]);
    } else if (t < BFD + NCOMB) {
        int c = t - BFD;
        for (int k = 0; k < HIDC; ++k) {
            float w = Wc[k * NCOMB + c];
#pragma unroll
            for (int i = 0; i < NPB; ++i) acc[i] += hs[i][k] * w;
        }
        float bb = cb[c];
#pragma unroll
        for (int i = 0; i < NPB; ++i) stf(&wco[(n0 + i) * NCOMB + c], acc[i] + bb);
    }
}

// 4. fused CSR aggregation (sum/mean/max) + einsum + bias -> conv (bf16)
template <typename TW>
__global__ __launch_bounds__(256) void k_agg(const int* __restrict__ rowptr,
                                             const int* __restrict__ csr,
                                             const bf16* __restrict__ bases,
                                             const TW* __restrict__ wco,
                                             const float* __restrict__ bias,
                                             bf16* __restrict__ conv) {
    __shared__ float agg[2][3][BFD];
    int sub = threadIdx.x >> 7;
    int tj = threadIdx.x & 127;
    int n = blockIdx.x * 2 + sub;
    int r0 = rowptr[n], r1 = rowptr[n + 1];
    float s = 0.f, mx = -INFINITY;
    for (int e = r0; e < r1; ++e) {
        int sn = csr[e];
        float v = b2f(bases[(size_t)sn * BFD + tj]);
        s += v;
        mx = fmaxf(mx, v);
    }
    float deg = (float)(r1 - r0);           // >=1 (self-loops)
    agg[sub][0][tj] = s;
    agg[sub][1][tj] = s / fmaxf(deg, 1.f);
    agg[sub][2][tj] = mx;
    __syncthreads();
#pragma unroll
    for (int half = 0; half < 2; ++half) {
        int c = tj + half * BFD;
        int hh = c >> 5, d = c & 31;
        const TW* w = &wco[(size_t)n * NCOMB + hh * 12];
        float acc = 0.f;
#pragma unroll
        for (int b = 0; b < 4; ++b) {
            acc += ldf(&w[0 * 4 + b]) * agg[sub][0][b * 32 + d];
            acc += ldf(&w[1 * 4 + b]) * agg[sub][1][b * 32 + d];
            acc += ldf(&w[2 * 4 + b]) * agg[sub][2][b * 32 + d];
        }
        conv[(size_t)n * HIDC + c] = f2b(acc + bias[c]);
    }
}

// 5. BN stats over conv (bf16)
__global__ __launch_bounds__(256) void k_stats_bf(const bf16* __restrict__ conv,
                                                  float* __restrict__ sums, int rows,
                                                  int rpb) {
    int c = threadIdx.x;
    int r0 = blockIdx.x * rpb;
    int r1 = min(r0 + rpb, rows);
    float s = 0.f, s2 = 0.f;
    for (int r = r0; r < r1; ++r) {
        float v = b2f(conv[(size_t)r * HIDC + c]);
        s += v;
        s2 += v * v;
    }
    atomicAdd(&sums[c], s);
    atomicAdd(&sums[HIDC + c], s2);
}

// 6. BN finalize
template <int C>
__global__ void k_bnfin(const float* __restrict__ sums, const float* __restrict__ g,
                        const float* __restrict__ b, float nrows, float* __restrict__ ss) {
    int c = threadIdx.x;
    float mu = sums[c] / nrows;
    float var = sums[C + c] / nrows - mu * mu;
    float rstd = rsqrtf(fmaxf(var, 0.f) + EPSV);
    float sc = rstd * g[c];
    ss[c] = sc;
    ss[C + c] = b[c] - mu * sc;
}

// 7. BN apply + ReLU + residual into h
template <typename TH>
__global__ __launch_bounds__(256) void k_apply_res(const bf16* __restrict__ conv,
                                                   const float* __restrict__ ss,
                                                   TH* __restrict__ h) {
    int n = blockIdx.x;
    int c = threadIdx.x;
    float v = b2f(conv[(size_t)n * HIDC + c]) * ss[c] + ss[HIDC + c];
    size_t i = (size_t)n * HIDC + c;
    stf(&h[i], ldf(&h[i]) + fmaxf(v, 0.f));
}

// 8. pooling
template <typename TH>
__global__ __launch_bounds__(256) void k_pool(const TH* __restrict__ h,
                                              const int* __restrict__ batch,
                                              float* __restrict__ gs,
                                              float* __restrict__ cnt) {
    int n = blockIdx.x;
    int c = threadIdx.x;
    int b = batch[n];
    atomicAdd(&gs[b * HIDC + c], ldf(&h[(size_t)n * HIDC + c]));
    if (c == 0) atomicAdd(&cnt[b], 1.0f);
}

__global__ __launch_bounds__(256) void k_pooldiv(float* __restrict__ gs,
                                                 const float* __restrict__ cnt) {
    int i = blockIdx.x * 256 + threadIdx.x;
    if (i >= NGR * HIDC) return;
    int ng = i >> 8;
    gs[i] = gs[i] / fmaxf(cnt[ng], 1.0f);
}

// 9. head row-GEMM
template <int K, int C>
__global__ void k_rowgemm(const float* __restrict__ in, const float* __restrict__ W,
                          float* __restrict__ out) {
    int r = blockIdx.x;
    __shared__ float rs[K];
    for (int i = threadIdx.x; i < K; i += C) rs[i] = in[r * K + i];
    __syncthreads();
    int c = threadIdx.x;
    float acc = 0.f;
    for (int k = 0; k < K; ++k) acc += rs[k] * W[k * C + c];
    out[r * C + c] = acc;
}

// 10. head BN stats (fp32)
template <int C>
__global__ void k_stats(const float* __restrict__ a, int rows, int rpb,
                        float* __restrict__ sums) {
    int c = threadIdx.x;
    int r0 = blockIdx.x * rpb;
    int r1 = min(r0 + rpb, rows);
    float s = 0.f, s2 = 0.f;
    for (int r = r0; r < r1; ++r) {
        float v = a[r * C + c];
        s += v;
        s2 += v * v;
    }
    atomicAdd(&sums[c], s);
    atomicAdd(&sums[C + c], s2);
}

// 11. head BN apply + ReLU
template <int C>
__global__ void k_apply_relu(float* __restrict__ a, const float* __restrict__ ss, int rows) {
    int i = blockIdx.x * 256 + threadIdx.x;
    if (i >= rows * C) return;
    int c = i % C;
    float v = a[i] * ss[c] + ss[C + c];
    a[i] = fmaxf(v, 0.f);
}

// 12. final linear
__global__ __launch_bounds__(256) void k_final(const float* __restrict__ g2,
                                               const float* __restrict__ w3,
                                               const float* __restrict__ b3,
                                               float* __restrict__ out) {
    int r = blockIdx.x * 256 + threadIdx.x;
    if (r >= NGR) return;
    float acc = 0.f;
#pragma unroll
    for (int k = 0; k < 64; ++k) acc += g2[r * 64 + k] * w3[k];
    out[r] = acc + b3[0];
}

static inline size_t alignup(size_t v) { return (v + 255) & ~(size_t)255; }

template <typename TH, typename TW>
static size_t carve_need(int E) {
    size_t off = 0;
    off = alignup(off + (size_t)NNODES * HIDC * sizeof(TH));   // h
    off = alignup(off + (size_t)NNODES * BFD * 2);             // bases bf16
    off = alignup(off + (size_t)NNODES * NCOMB * sizeof(TW));  // wco
    size_t conv0 = off;
    off = alignup(off + (size_t)NNODES * HIDC * 2);            // conv bf16
    off = alignup(off + (size_t)(NNODES + 1) * 4);             // rowptr
    off = alignup(off + (size_t)NNODES * 4);                   // cursor
    off = alignup(off + (size_t)E * 4);                        // csr
    off = alignup(off + 2 * HIDC * 4);                         // sums
    off = alignup(off + 2 * HIDC * 4);                         // ss
    // gs/cnt/r1/r2 alias the conv region (conv dead after last layer):
    size_t pool = alignup((size_t)NGR * HIDC * 4) + alignup((size_t)NGR * 4)
                + alignup((size_t)NGR * 128 * 4) + alignup((size_t)NGR * 64 * 4);
    (void)conv0;
    return off + ((pool > (size_t)NNODES * HIDC * 2) ? pool : 0);
}

template <typename TH, typename TW>
static void run_all(const int* x, const int* esrc, const int* edst, const int* batch,
                    const float* emb, const float* basesW, const float* combW,
                    const float* combB, const float* convB, const float* bnG,
                    const float* bnB, const float* w1, const float* bn1g,
                    const float* bn1b, const float* w2, const float* bn2g,
                    const float* bn2b, const float* w3, const float* b3, int E,
                    float* out, char* base, hipStream_t stream) {
    size_t off = 0;
    TH* h = (TH*)(base + off);       off = alignup(off + (size_t)NNODES * HIDC * sizeof(TH));
    bf16* bases = (bf16*)(base + off); off = alignup(off + (size_t)NNODES * BFD * 2);
    TW* wco = (TW*)(base + off);     off = alignup(off + (size_t)NNODES * NCOMB * sizeof(TW));
    size_t o_conv = off;
    bf16* conv = (bf16*)(base + off); off = alignup(off + (size_t)NNODES * HIDC * 2);
    int* rowptr = (int*)(base + off); off = alignup(off + (size_t)(NNODES + 1) * 4);
    int* cursor = (int*)(base + off); off = alignup(off + (size_t)NNODES * 4);
    int* csr = (int*)(base + off);    off = alignup(off + (size_t)E * 4);
    float* sums = (float*)(base + off); off = alignup(off + 2 * HIDC * 4);
    float* ss = (float*)(base + off);   off = alignup(off + 2 * HIDC * 4);
    // pool/head buffers alias conv region (dead after layers)
    size_t po = o_conv;
    float* gs = (float*)(base + po);  po = alignup(po + (size_t)NGR * HIDC * 4);
    float* cnt = (float*)(base + po); po = alignup(po + (size_t)NGR * 4);
    float* r1 = (float*)(base + po);  po = alignup(po + (size_t)NGR * 128 * 4);
    float* r2 = (float*)(base + po);  po = alignup(po + (size_t)NGR * 64 * 4);

    // once: embeddings + CSR build
    k_atom<TH><<<NNODES, 256, 0, stream>>>(x, emb, h);
    hipMemsetAsync(cursor, 0, (size_t)NNODES * 4, stream);
    k_hist<<<(E + 255) / 256, 256, 0, stream>>>(edst, cursor, E);
    k_scan<<<1, 256, 0, stream>>>(cursor, rowptr, NNODES);
    k_copy<<<(NNODES + 255) / 256, 256, 0, stream>>>(rowptr, cursor, NNODES);
    k_scatter<<<(E + 255) / 256, 256, 0, stream>>>(esrc, edst, cursor, csr, E);

    for (int l = 0; l < LAYERSN; ++l) {
        hipMemsetAsync(sums, 0, 2 * HIDC * 4, stream);
        k_gemm_bw<TH, TW><<<NNODES / NPB, 256, 0, stream>>>(
            h, basesW + (size_t)l * HIDC * BFD, combW + (size_t)l * HIDC * NCOMB,
            combB + (size_t)l * NCOMB, bases, wco);
        k_agg<TW><<<NNODES / 2, 256, 0, stream>>>(rowptr, csr, bases, wco,
                                                  convB + (size_t)l * HIDC, conv);
        k_stats_bf<<<(NNODES + 255) / 256, 256, 0, stream>>>(conv, sums, NNODES, 256);
        k_bnfin<HIDC><<<1, HIDC, 0, stream>>>(sums, bnG + (size_t)l * HIDC,
                                              bnB + (size_t)l * HIDC, (float)NNODES, ss);
        k_apply_res<TH><<<NNODES, 256, 0, stream>>>(conv, ss, h);
    }

    hipMemsetAsync(gs, 0, (size_t)NGR * HIDC * 4, stream);
    hipMemsetAsync(cnt, 0, (size_t)NGR * 4, stream);
    k_pool<TH><<<NNODES, 256, 0, stream>>>(h, batch, gs, cnt);
    k_pooldiv<<<(NGR * HIDC + 255) / 256, 256, 0, stream>>>(gs, cnt);

    k_rowgemm<256, 128><<<NGR, 128, 0, stream>>>(gs, w1, r1);
    hipMemsetAsync(sums, 0, 2 * 128 * 4, stream);
    k_stats<128><<<(NGR + 15) / 16, 128, 0, stream>>>(r1, NGR, 16, sums);
    k_bnfin<128><<<1, 128, 0, stream>>>(sums, bn1g, bn1b, (float)NGR, ss);
    k_apply_relu<128><<<(NGR * 128 + 255) / 256, 256, 0, stream>>>(r1, ss, NGR);

    k_rowgemm<128, 64><<<NGR, 64, 0, stream>>>(r1, w2, r2);
    hipMemsetAsync(sums, 0, 2 * 64 * 4, stream);
    k_stats<64><<<(NGR + 31) / 32, 64, 0, stream>>>(r2, NGR, 32, sums);
    k_bnfin<64><<<1, 64, 0, stream>>>(sums, bn2g, bn2b, (float)NGR, ss);
    k_apply_relu<64><<<(NGR * 64 + 255) / 256, 256, 0, stream>>>(r2, ss, NGR);

    k_final<<<(NGR + 255) / 256, 256, 0, stream>>>(r2, w3, b3, out);
}

extern "C" void kernel_launch(void* const* d_in, const int* in_sizes, int n_in,
                              void* d_out, int out_size, void* d_ws, size_t ws_size,
                              hipStream_t stream) {
    const int* x        = (const int*)d_in[0];
    const int* esrc     = (const int*)d_in[1];
    const int* edst     = (const int*)d_in[2];
    const int* batch    = (const int*)d_in[3];
    const float* emb    = (const float*)d_in[4];
    const float* basesW = (const float*)d_in[5];
    const float* combW  = (const float*)d_in[6];
    const float* combB  = (const float*)d_in[7];
    const float* convB  = (const float*)d_in[8];
    const float* bnG    = (const float*)d_in[9];
    const float* bnB    = (const float*)d_in[10];
    const float* w1     = (const float*)d_in[11];
    const float* bn1g   = (const float*)d_in[12];
    const float* bn1b   = (const float*)d_in[13];
    const float* w2     = (const float*)d_in[14];
    const float* bn2g   = (const float*)d_in[15];
    const float* bn2b   = (const float*)d_in[16];
    const float* w3     = (const float*)d_in[17];
    const float* b3     = (const float*)d_in[18];
    const int E = in_sizes[1];

    size_t need_full    = carve_need<float, float>(E);  // ~225 MB
    size_t need_compact = carve_need<bf16, bf16>(E);    // ~155 MB

    if (ws_size >= need_full) {
        run_all<float, float>(x, esrc, edst, batch, emb, basesW, combW, combB, convB,
                              bnG, bnB, w1, bn1g, bn1b, w2, bn2g, bn2b, w3, b3, E,
                              (float*)d_out, (char*)d_ws, stream);
    } else if (ws_size >= need_compact) {
        run_all<bf16, bf16>(x, esrc, edst, batch, emb, basesW, combW, combB, convB,
                            bnG, bnB, w1, bn1g, bn1b, w2, bn2g, bn2b, w3, b3, E,
                            (float*)d_out, (char*)d_ws, stream);
    } else {
        // diagnostic: absmax will read ~= ws_size in MB
        k_sentinel<<<(out_size + 255) / 256, 256, 0, stream>>>(
            (float*)d_out, out_size, (float)(ws_size >> 20));
    }
}

// Round 7
// 2183.665 us; speedup vs baseline: 1.6385x; 1.6385x over previous
//
#include <hip/hip_runtime.h>
#include <hip/hip_bf16.h>

#define NNODES 100000
#define HIDC 256
#define NFEAT 9
#define VOCABS 128
#define BFD 128        // bases output dim
#define NCOMB 96       // heads*bases*aggs
#define NGR 5000
#define LAYERSN 4
#define EPSV 1e-5f
#define NPB 16         // nodes per block in node GEMM
#define SCHUNK 1024    // scan chunk
#define NPP 16         // nodes per block in pooling

typedef __hip_bfloat16 bf16;

__device__ __forceinline__ float b2f(bf16 v) { return __bfloat162float(v); }
__device__ __forceinline__ bf16 f2b(float v) { return __float2bfloat16(v); }
__device__ __forceinline__ float ldf(const float* p) { return *p; }
__device__ __forceinline__ float ldf(const bf16* p) { return b2f(*p); }
__device__ __forceinline__ void stf(float* p, float v) { *p = v; }
__device__ __forceinline__ void stf(bf16* p, float v) { *p = f2b(v); }

// 0. sentinel: encode ws_size(MB) into output if workspace too small
__global__ __launch_bounds__(256) void k_sentinel(float* out, int n, float val) {
    int i = blockIdx.x * 256 + threadIdx.x;
    if (i < n) out[i] = val;
}

// 1. AtomEncoder
template <typename TH>
__global__ __launch_bounds__(256) void k_atom(const int* __restrict__ x,
                                              const float* __restrict__ emb,
                                              TH* __restrict__ h) {
    int n = blockIdx.x;
    __shared__ int xs[NFEAT];
    if (threadIdx.x < NFEAT) xs[threadIdx.x] = x[n * NFEAT + threadIdx.x];
    __syncthreads();
    int c = threadIdx.x;
    float acc = 0.f;
#pragma unroll
    for (int f = 0; f < NFEAT; ++f)
        acc += emb[(f * VOCABS + xs[f]) * HIDC + c];
    stf(&h[(size_t)n * HIDC + c], acc);
}

// 2a. histogram of dst
__global__ __launch_bounds__(256) void k_hist(const int* __restrict__ dst,
                                              int* __restrict__ counts, int E) {
    int e = blockIdx.x * 256 + threadIdx.x;
    if (e < E) atomicAdd(&counts[dst[e]], 1);
}

// 2b-1. per-1024-chunk totals
__global__ __launch_bounds__(256) void k_scansum(const int* __restrict__ counts,
                                                 int* __restrict__ btot, int n) {
    __shared__ int sh[256];
    int b = blockIdx.x, t = threadIdx.x;
    int base = b * SCHUNK;
    int s = 0;
#pragma unroll
    for (int k = 0; k < 4; ++k) {
        int i = base + t + k * 256;
        if (i < n) s += counts[i];
    }
    sh[t] = s;
    __syncthreads();
    for (int st = 128; st > 0; st >>= 1) {
        if (t < st) sh[t] += sh[t + st];
        __syncthreads();
    }
    if (t == 0) btot[b] = sh[0];
}

// 2b-2. serial exclusive scan of chunk totals (~98 elements)
__global__ void k_scansmall(const int* __restrict__ btot, int* __restrict__ boff, int nb) {
    if (threadIdx.x == 0 && blockIdx.x == 0) {
        int a = 0;
        for (int i = 0; i < nb; ++i) { boff[i] = a; a += btot[i]; }
    }
}

// 2b-3. per-chunk scan + global offset -> rowptr
__global__ __launch_bounds__(256) void k_scanapply(const int* __restrict__ counts,
                                                   const int* __restrict__ boff,
                                                   int* __restrict__ rowptr, int n) {
    __shared__ int sh[256];
    int b = blockIdx.x, t = threadIdx.x;
    int base = b * SCHUNK + t * 4;
    int c0 = (base + 0 < n) ? counts[base + 0] : 0;
    int c1 = (base + 1 < n) ? counts[base + 1] : 0;
    int c2 = (base + 2 < n) ? counts[base + 2] : 0;
    int c3 = (base + 3 < n) ? counts[base + 3] : 0;
    int s0 = c0, s1 = s0 + c1, s2 = s1 + c2, s3 = s2 + c3;
    sh[t] = s3;
    __syncthreads();
    for (int st = 1; st < 256; st <<= 1) {
        int v = (t >= st) ? sh[t - st] : 0;
        __syncthreads();
        sh[t] += v;
        __syncthreads();
    }
    int excl = sh[t] - s3 + boff[b];
    if (base + 0 < n) rowptr[base + 1] = excl + s0;
    if (base + 1 < n) rowptr[base + 2] = excl + s1;
    if (base + 2 < n) rowptr[base + 3] = excl + s2;
    if (base + 3 < n) rowptr[base + 4] = excl + s3;
    if (b == 0 && t == 0) rowptr[0] = 0;
}

// 2c. cursor = rowptr[0..N-1]
__global__ __launch_bounds__(256) void k_copy(const int* __restrict__ rowptr,
                                              int* __restrict__ cursor, int n) {
    int i = blockIdx.x * 256 + threadIdx.x;
    if (i < n) cursor[i] = rowptr[i];
}

// 2d. scatter src into CSR slots
__global__ __launch_bounds__(256) void k_scatter(const int* __restrict__ src,
                                                 const int* __restrict__ dst,
                                                 int* __restrict__ cursor,
                                                 int* __restrict__ csr, int E) {
    int e = blockIdx.x * 256 + threadIdx.x;
    if (e >= E) return;
    int pos = atomicAdd(&cursor[dst[e]], 1);
    csr[pos] = src[e];
}

// 3. node GEMM: bases(bf16) = h@Wb, wco = h@Wc + cb. 16 nodes/block.
template <typename TH, typename TW>
__global__ __launch_bounds__(256) void k_gemm_bw(const TH* __restrict__ h,
                                                 const float* __restrict__ Wb,
                                                 const float* __restrict__ Wc,
                                                 const float* __restrict__ cb,
                                                 bf16* __restrict__ bases,
                                                 TW* __restrict__ wco) {
    __shared__ float hs[NPB][HIDC];
    size_t n0 = (size_t)blockIdx.x * NPB;
    for (int i = threadIdx.x; i < NPB * HIDC; i += 256)
        ((float*)hs)[i] = ldf(&h[n0 * HIDC + i]);
    __syncthreads();
    int t = threadIdx.x;
    float acc[NPB];
#pragma unroll
    for (int i = 0; i < NPB; ++i) acc[i] = 0.f;
    if (t < BFD) {
        for (int k = 0; k < HIDC; ++k) {
            float w = Wb[k * BFD + t];
#pragma unroll
            for (int i = 0; i < NPB; ++i) acc[i] += hs[i][k] * w;
        }
#pragma unroll
        for (int i = 0; i < NPB; ++i) bases[(n0 + i) * BFD + t] = f2b(acc[i]);
    } else if (t < BFD + NCOMB) {
        int c = t - BFD;
        for (int k = 0; k < HIDC; ++k) {
            float w = Wc[k * NCOMB + c];
#pragma unroll
            for (int i = 0; i < NPB; ++i) acc[i] += hs[i][k] * w;
        }
        float bb = cb[c];
#pragma unroll
        for (int i = 0; i < NPB; ++i) stf(&wco[(n0 + i) * NCOMB + c], acc[i] + bb);
    }
}

// 4. fused CSR aggregation + einsum. One wave per node (4 nodes/block).
//    Gathers as uint32 = 2×bf16 per lane; edge loop unrolled ×4 for ILP.
template <typename TW>
__global__ __launch_bounds__(256) void k_agg(const int* __restrict__ rowptr,
                                             const int* __restrict__ csr,
                                             const unsigned* __restrict__ basesu,
                                             const TW* __restrict__ wco,
                                             const float* __restrict__ bias,
                                             bf16* __restrict__ conv) {
    __shared__ float agg[4][3][BFD];
    int wv = threadIdx.x >> 6;
    int lane = threadIdx.x & 63;
    int n = blockIdx.x * 4 + wv;
    int r0 = rowptr[n], r1 = rowptr[n + 1];
    float s0 = 0.f, s1 = 0.f, mx0 = -INFINITY, mx1 = -INFINITY;
    int e = r0;
    for (; e + 4 <= r1; e += 4) {
        int i0 = csr[e + 0] * 64, i1 = csr[e + 1] * 64;
        int i2 = csr[e + 2] * 64, i3 = csr[e + 3] * 64;
        unsigned v0 = basesu[i0 + lane], v1 = basesu[i1 + lane];
        unsigned v2 = basesu[i2 + lane], v3 = basesu[i3 + lane];
#define ACCV(v) { float lo = __uint_as_float((v) << 16);            \
                  float hi = __uint_as_float((v) & 0xFFFF0000u);    \
                  s0 += lo; s1 += hi;                               \
                  mx0 = fmaxf(mx0, lo); mx1 = fmaxf(mx1, hi); }
        ACCV(v0) ACCV(v1) ACCV(v2) ACCV(v3)
    }
    for (; e < r1; ++e) {
        unsigned v = basesu[csr[e] * 64 + lane];
        ACCV(v)
    }
#undef ACCV
    float inv = 1.0f / fmaxf((float)(r1 - r0), 1.0f);
    agg[wv][0][2 * lane] = s0;      agg[wv][0][2 * lane + 1] = s1;
    agg[wv][1][2 * lane] = s0 * inv; agg[wv][1][2 * lane + 1] = s1 * inv;
    agg[wv][2][2 * lane] = mx0;     agg[wv][2][2 * lane + 1] = mx1;
    __syncthreads();
    int c = threadIdx.x;
    int hh = c >> 5, d = c & 31;
    float bb = bias[c];
#pragma unroll
    for (int w2 = 0; w2 < 4; ++w2) {
        int n2 = blockIdx.x * 4 + w2;
        const TW* wp = &wco[(size_t)n2 * NCOMB + hh * 12];
        float a = 0.f;
#pragma unroll
        for (int b = 0; b < 4; ++b) {
            a += ldf(&wp[0 + b]) * agg[w2][0][b * 32 + d];
            a += ldf(&wp[4 + b]) * agg[w2][1][b * 32 + d];
            a += ldf(&wp[8 + b]) * agg[w2][2][b * 32 + d];
        }
        conv[(size_t)n2 * HIDC + c] = f2b(a + bb);
    }
}

// 5. BN stats over conv (bf16)
__global__ __launch_bounds__(256) void k_stats_bf(const bf16* __restrict__ conv,
                                                  float* __restrict__ sums, int rows,
                                                  int rpb) {
    int c = threadIdx.x;
    int r0 = blockIdx.x * rpb;
    int r1 = min(r0 + rpb, rows);
    float s = 0.f, s2 = 0.f;
    for (int r = r0; r < r1; ++r) {
        float v = b2f(conv[(size_t)r * HIDC + c]);
        s += v;
        s2 += v * v;
    }
    atomicAdd(&sums[c], s);
    atomicAdd(&sums[HIDC + c], s2);
}

// 6. BN finalize
template <int C>
__global__ void k_bnfin(const float* __restrict__ sums, const float* __restrict__ g,
                        const float* __restrict__ b, float nrows, float* __restrict__ ss) {
    int c = threadIdx.x;
    float mu = sums[c] / nrows;
    float var = sums[C + c] / nrows - mu * mu;
    float rstd = rsqrtf(fmaxf(var, 0.f) + EPSV);
    float sc = rstd * g[c];
    ss[c] = sc;
    ss[C + c] = b[c] - mu * sc;
}

// 7. BN apply + ReLU + residual into h
template <typename TH>
__global__ __launch_bounds__(256) void k_apply_res(const bf16* __restrict__ conv,
                                                   const float* __restrict__ ss,
                                                   TH* __restrict__ h) {
    int n = blockIdx.x;
    int c = threadIdx.x;
    float v = b2f(conv[(size_t)n * HIDC + c]) * ss[c] + ss[HIDC + c];
    size_t i = (size_t)n * HIDC + c;
    stf(&h[i], ldf(&h[i]) + fmaxf(v, 0.f));
}

// 8. pooling: batch is sorted -> register accumulate, flush at boundaries
template <typename TH>
__global__ __launch_bounds__(256) void k_pool(const TH* __restrict__ h,
                                              const int* __restrict__ batch,
                                              float* __restrict__ gs,
                                              float* __restrict__ cnt) {
    int c = threadIdx.x;
    int n0 = blockIdx.x * NPP;
    int end = min(n0 + NPP, NNODES);
    float acc = 0.f, ccnt = 0.f;
    int cur = batch[n0];
    for (int n = n0; n < end; ++n) {
        int b = batch[n];
        if (b != cur) {
            atomicAdd(&gs[(size_t)cur * HIDC + c], acc);
            if (c == 0) atomicAdd(&cnt[cur], ccnt);
            acc = 0.f; ccnt = 0.f; cur = b;
        }
        acc += ldf(&h[(size_t)n * HIDC + c]);
        ccnt += 1.f;
    }
    atomicAdd(&gs[(size_t)cur * HIDC + c], acc);
    if (c == 0) atomicAdd(&cnt[cur], ccnt);
}

__global__ __launch_bounds__(256) void k_pooldiv(float* __restrict__ gs,
                                                 const float* __restrict__ cnt) {
    int i = blockIdx.x * 256 + threadIdx.x;
    if (i >= NGR * HIDC) return;
    int ng = i >> 8;
    gs[i] = gs[i] / fmaxf(cnt[ng], 1.0f);
}

// 9. head row-GEMM
template <int K, int C>
__global__ void k_rowgemm(const float* __restrict__ in, const float* __restrict__ W,
                          float* __restrict__ out) {
    int r = blockIdx.x;
    __shared__ float rs[K];
    for (int i = threadIdx.x; i < K; i += C) rs[i] = in[r * K + i];
    __syncthreads();
    int c = threadIdx.x;
    float acc = 0.f;
    for (int k = 0; k < K; ++k) acc += rs[k] * W[k * C + c];
    out[r * C + c] = acc;
}

// 10. head BN stats
template <int C>
__global__ void k_stats(const float* __restrict__ a, int rows, int rpb,
                        float* __restrict__ sums) {
    int c = threadIdx.x;
    int r0 = blockIdx.x * rpb;
    int r1 = min(r0 + rpb, rows);
    float s = 0.f, s2 = 0.f;
    for (int r = r0; r < r1; ++r) {
        float v = a[r * C + c];
        s += v;
        s2 += v * v;
    }
    atomicAdd(&sums[c], s);
    atomicAdd(&sums[C + c], s2);
}

// 11. head BN apply + ReLU
template <int C>
__global__ void k_apply_relu(float* __restrict__ a, const float* __restrict__ ss, int rows) {
    int i = blockIdx.x * 256 + threadIdx.x;
    if (i >= rows * C) return;
    int c = i % C;
    float v = a[i] * ss[c] + ss[C + c];
    a[i] = fmaxf(v, 0.f);
}

// 12. final linear
__global__ __launch_bounds__(256) void k_final(const float* __restrict__ g2,
                                               const float* __restrict__ w3,
                                               const float* __restrict__ b3,
                                               float* __restrict__ out) {
    int r = blockIdx.x * 256 + threadIdx.x;
    if (r >= NGR) return;
    float acc = 0.f;
#pragma unroll
    for (int k = 0; k < 64; ++k) acc += g2[r * 64 + k] * w3[k];
    out[r] = acc + b3[0];
}

static inline size_t alignup(size_t v) { return (v + 255) & ~(size_t)255; }

template <typename TH, typename TW>
static size_t carve_need(int E) {
    size_t off = 0;
    off = alignup(off + (size_t)NNODES * HIDC * sizeof(TH));   // h
    off = alignup(off + (size_t)NNODES * BFD * 2);             // bases bf16
    off = alignup(off + (size_t)NNODES * NCOMB * sizeof(TW));  // wco
    off = alignup(off + (size_t)NNODES * HIDC * 2);            // conv bf16
    off = alignup(off + (size_t)(NNODES + 1) * 4);             // rowptr
    off = alignup(off + (size_t)NNODES * 4);                   // cursor
    off = alignup(off + (size_t)E * 4);                        // csr
    off = alignup(off + 2 * HIDC * 4);                         // sums
    off = alignup(off + 2 * HIDC * 4);                         // ss
    off = alignup(off + 256 * 4);                              // btot
    off = alignup(off + 256 * 4);                              // boff
    return off;  // pool/head alias conv region (6.8 MB < 51.2 MB)
}

template <typename TH, typename TW>
static void run_all(const int* x, const int* esrc, const int* edst, const int* batch,
                    const float* emb, const float* basesW, const float* combW,
                    const float* combB, const float* convB, const float* bnG,
                    const float* bnB, const float* w1, const float* bn1g,
                    const float* bn1b, const float* w2, const float* bn2g,
                    const float* bn2b, const float* w3, const float* b3, int E,
                    float* out, char* base, hipStream_t stream) {
    size_t off = 0;
    TH* h = (TH*)(base + off);       off = alignup(off + (size_t)NNODES * HIDC * sizeof(TH));
    bf16* bases = (bf16*)(base + off); off = alignup(off + (size_t)NNODES * BFD * 2);
    TW* wco = (TW*)(base + off);     off = alignup(off + (size_t)NNODES * NCOMB * sizeof(TW));
    size_t o_conv = off;
    bf16* conv = (bf16*)(base + off); off = alignup(off + (size_t)NNODES * HIDC * 2);
    int* rowptr = (int*)(base + off); off = alignup(off + (size_t)(NNODES + 1) * 4);
    int* cursor = (int*)(base + off); off = alignup(off + (size_t)NNODES * 4);
    int* csr = (int*)(base + off);    off = alignup(off + (size_t)E * 4);
    float* sums = (float*)(base + off); off = alignup(off + 2 * HIDC * 4);
    float* ss = (float*)(base + off);   off = alignup(off + 2 * HIDC * 4);
    int* btot = (int*)(base + off);     off = alignup(off + 256 * 4);
    int* boff = (int*)(base + off);     off = alignup(off + 256 * 4);
    // pool/head buffers alias conv region (dead after layers)
    size_t po = o_conv;
    float* gs = (float*)(base + po);  po = alignup(po + (size_t)NGR * HIDC * 4);
    float* cnt = (float*)(base + po); po = alignup(po + (size_t)NGR * 4);
    float* r1 = (float*)(base + po);  po = alignup(po + (size_t)NGR * 128 * 4);
    float* r2 = (float*)(base + po);  po = alignup(po + (size_t)NGR * 64 * 4);

    const int NB = (NNODES + SCHUNK - 1) / SCHUNK;  // 98

    // once: embeddings + CSR build
    k_atom<TH><<<NNODES, 256, 0, stream>>>(x, emb, h);
    hipMemsetAsync(cursor, 0, (size_t)NNODES * 4, stream);
    k_hist<<<(E + 255) / 256, 256, 0, stream>>>(edst, cursor, E);
    k_scansum<<<NB, 256, 0, stream>>>(cursor, btot, NNODES);
    k_scansmall<<<1, 64, 0, stream>>>(btot, boff, NB);
    k_scanapply<<<NB, 256, 0, stream>>>(cursor, boff, rowptr, NNODES);
    k_copy<<<(NNODES + 255) / 256, 256, 0, stream>>>(rowptr, cursor, NNODES);
    k_scatter<<<(E + 255) / 256, 256, 0, stream>>>(esrc, edst, cursor, csr, E);

    for (int l = 0; l < LAYERSN; ++l) {
        hipMemsetAsync(sums, 0, 2 * HIDC * 4, stream);
        k_gemm_bw<TH, TW><<<NNODES / NPB, 256, 0, stream>>>(
            h, basesW + (size_t)l * HIDC * BFD, combW + (size_t)l * HIDC * NCOMB,
            combB + (size_t)l * NCOMB, bases, wco);
        k_agg<TW><<<NNODES / 4, 256, 0, stream>>>(rowptr, csr, (const unsigned*)bases,
                                                  wco, convB + (size_t)l * HIDC, conv);
        k_stats_bf<<<(NNODES + 255) / 256, 256, 0, stream>>>(conv, sums, NNODES, 256);
        k_bnfin<HIDC><<<1, HIDC, 0, stream>>>(sums, bnG + (size_t)l * HIDC,
                                              bnB + (size_t)l * HIDC, (float)NNODES, ss);
        k_apply_res<TH><<<NNODES, 256, 0, stream>>>(conv, ss, h);
    }

    hipMemsetAsync(gs, 0, (size_t)NGR * HIDC * 4, stream);
    hipMemsetAsync(cnt, 0, (size_t)NGR * 4, stream);
    k_pool<TH><<<(NNODES + NPP - 1) / NPP, 256, 0, stream>>>(h, batch, gs, cnt);
    k_pooldiv<<<(NGR * HIDC + 255) / 256, 256, 0, stream>>>(gs, cnt);

    k_rowgemm<256, 128><<<NGR, 128, 0, stream>>>(gs, w1, r1);
    hipMemsetAsync(sums, 0, 2 * 128 * 4, stream);
    k_stats<128><<<(NGR + 15) / 16, 128, 0, stream>>>(r1, NGR, 16, sums);
    k_bnfin<128><<<1, 128, 0, stream>>>(sums, bn1g, bn1b, (float)NGR, ss);
    k_apply_relu<128><<<(NGR * 128 + 255) / 256, 256, 0, stream>>>(r1, ss, NGR);

    k_rowgemm<128, 64><<<NGR, 64, 0, stream>>>(r1, w2, r2);
    hipMemsetAsync(sums, 0, 2 * 64 * 4, stream);
    k_stats<64><<<(NGR + 31) / 32, 64, 0, stream>>>(r2, NGR, 32, sums);
    k_bnfin<64><<<1, 64, 0, stream>>>(sums, bn2g, bn2b, (float)NGR, ss);
    k_apply_relu<64><<<(NGR * 64 + 255) / 256, 256, 0, stream>>>(r2, ss, NGR);

    k_final<<<(NGR + 255) / 256, 256, 0, stream>>>(r2, w3, b3, out);
}

extern "C" void kernel_launch(void* const* d_in, const int* in_sizes, int n_in,
                              void* d_out, int out_size, void* d_ws, size_t ws_size,
                              hipStream_t stream) {
    const int* x        = (const int*)d_in[0];
    const int* esrc     = (const int*)d_in[1];
    const int* edst     = (const int*)d_in[2];
    const int* batch    = (const int*)d_in[3];
    const float* emb    = (const float*)d_in[4];
    const float* basesW = (const float*)d_in[5];
    const float* combW  = (const float*)d_in[6];
    const float* combB  = (const float*)d_in[7];
    const float* convB  = (const float*)d_in[8];
    const float* bnG    = (const float*)d_in[9];
    const float* bnB    = (const float*)d_in[10];
    const float* w1     = (const float*)d_in[11];
    const float* bn1g   = (const float*)d_in[12];
    const float* bn1b   = (const float*)d_in[13];
    const float* w2     = (const float*)d_in[14];
    const float* bn2g   = (const float*)d_in[15];
    const float* bn2b   = (const float*)d_in[16];
    const float* w3     = (const float*)d_in[17];
    const float* b3     = (const float*)d_in[18];
    const int E = in_sizes[1];

    size_t need_full    = carve_need<float, float>(E);  // ~225 MB
    size_t need_compact = carve_need<bf16, bf16>(E);    // ~155 MB

    if (ws_size >= need_full) {
        run_all<float, float>(x, esrc, edst, batch, emb, basesW, combW, combB, convB,
                              bnG, bnB, w1, bn1g, bn1b, w2, bn2g, bn2b, w3, b3, E,
                              (float*)d_out, (char*)d_ws, stream);
    } else if (ws_size >= need_compact) {
        run_all<bf16, bf16>(x, esrc, edst, batch, emb, basesW, combW, combB, convB,
                            bnG, bnB, w1, bn1g, bn1b, w2, bn2g, bn2b, w3, b3, E,
                            (float*)d_out, (char*)d_ws, stream);
    } else {
        k_sentinel<<<(out_size + 255) / 256, 256, 0, stream>>>(
            (float*)d_out, out_size, (float)(ws_size >> 20));
    }
}

// Round 8
// 1538.642 us; speedup vs baseline: 2.3254x; 1.4192x over previous
//
#include <hip/hip_runtime.h>
#include <hip/hip_bf16.h>

#define NNODES 100000
#define HIDC 256
#define NFEAT 9
#define VOCABS 128
#define BFD 128        // bases output dim
#define NCOMB 96       // heads*bases*aggs
#define NGR 5000
#define LAYERSN 4
#define EPSV 1e-5f
#define SCHUNK 1024    // scan chunk
#define NPP 16         // nodes per block in pooling
#define NTILES 14      // 224/16 output tiles (8 bases + 6 comb)

typedef __hip_bfloat16 bf16;
typedef __attribute__((ext_vector_type(8))) short sh8;   // 8 bf16 (4 VGPRs)
typedef __attribute__((ext_vector_type(4))) float fx4;   // MFMA acc

__device__ __forceinline__ float b2f(bf16 v) { return __bfloat162float(v); }
__device__ __forceinline__ bf16 f2b(float v) { return __float2bfloat16(v); }
__device__ __forceinline__ float ldf(const float* p) { return *p; }
__device__ __forceinline__ float ldf(const bf16* p) { return b2f(*p); }
__device__ __forceinline__ void stf(float* p, float v) { *p = v; }
__device__ __forceinline__ void stf(bf16* p, float v) { *p = f2b(v); }

// RNE pack of two f32 -> u32 of 2 bf16 (lo=first)
__device__ __forceinline__ unsigned pack2bf(float a, float b) {
    unsigned ua = __float_as_uint(a), ub = __float_as_uint(b);
    ua = (ua + 0x7FFFu + ((ua >> 16) & 1u)) >> 16;
    ub = (ub + 0x7FFFu + ((ub >> 16) & 1u)) >> 16;
    return ua | (ub << 16);
}

// 0. sentinel
__global__ __launch_bounds__(256) void k_sentinel(float* out, int n, float val) {
    int i = blockIdx.x * 256 + threadIdx.x;
    if (i < n) out[i] = val;
}

// 1. AtomEncoder
template <typename TH>
__global__ __launch_bounds__(256) void k_atom(const int* __restrict__ x,
                                              const float* __restrict__ emb,
                                              TH* __restrict__ h) {
    int n = blockIdx.x;
    __shared__ int xs[NFEAT];
    if (threadIdx.x < NFEAT) xs[threadIdx.x] = x[n * NFEAT + threadIdx.x];
    __syncthreads();
    int c = threadIdx.x;
    float acc = 0.f;
#pragma unroll
    for (int f = 0; f < NFEAT; ++f)
        acc += emb[(f * VOCABS + xs[f]) * HIDC + c];
    stf(&h[(size_t)n * HIDC + c], acc);
}

// 2a-2d: CSR build
__global__ __launch_bounds__(256) void k_hist(const int* __restrict__ dst,
                                              int* __restrict__ counts, int E) {
    int e = blockIdx.x * 256 + threadIdx.x;
    if (e < E) atomicAdd(&counts[dst[e]], 1);
}

__global__ __launch_bounds__(256) void k_scansum(const int* __restrict__ counts,
                                                 int* __restrict__ btot, int n) {
    __shared__ int sh[256];
    int b = blockIdx.x, t = threadIdx.x;
    int base = b * SCHUNK;
    int s = 0;
#pragma unroll
    for (int k = 0; k < 4; ++k) {
        int i = base + t + k * 256;
        if (i < n) s += counts[i];
    }
    sh[t] = s;
    __syncthreads();
    for (int st = 128; st > 0; st >>= 1) {
        if (t < st) sh[t] += sh[t + st];
        __syncthreads();
    }
    if (t == 0) btot[b] = sh[0];
}

__global__ void k_scansmall(const int* __restrict__ btot, int* __restrict__ boff, int nb) {
    if (threadIdx.x == 0 && blockIdx.x == 0) {
        int a = 0;
        for (int i = 0; i < nb; ++i) { boff[i] = a; a += btot[i]; }
    }
}

__global__ __launch_bounds__(256) void k_scanapply(const int* __restrict__ counts,
                                                   const int* __restrict__ boff,
                                                   int* __restrict__ rowptr, int n) {
    __shared__ int sh[256];
    int b = blockIdx.x, t = threadIdx.x;
    int base = b * SCHUNK + t * 4;
    int c0 = (base + 0 < n) ? counts[base + 0] : 0;
    int c1 = (base + 1 < n) ? counts[base + 1] : 0;
    int c2 = (base + 2 < n) ? counts[base + 2] : 0;
    int c3 = (base + 3 < n) ? counts[base + 3] : 0;
    int s0 = c0, s1 = s0 + c1, s2 = s1 + c2, s3 = s2 + c3;
    sh[t] = s3;
    __syncthreads();
    for (int st = 1; st < 256; st <<= 1) {
        int v = (t >= st) ? sh[t - st] : 0;
        __syncthreads();
        sh[t] += v;
        __syncthreads();
    }
    int excl = sh[t] - s3 + boff[b];
    if (base + 0 < n) rowptr[base + 1] = excl + s0;
    if (base + 1 < n) rowptr[base + 2] = excl + s1;
    if (base + 2 < n) rowptr[base + 3] = excl + s2;
    if (base + 3 < n) rowptr[base + 4] = excl + s3;
    if (b == 0 && t == 0) rowptr[0] = 0;
}

__global__ __launch_bounds__(256) void k_copy(const int* __restrict__ rowptr,
                                              int* __restrict__ cursor, int n) {
    int i = blockIdx.x * 256 + threadIdx.x;
    if (i < n) cursor[i] = rowptr[i];
}

__global__ __launch_bounds__(256) void k_scatter(const int* __restrict__ src,
                                                 const int* __restrict__ dst,
                                                 int* __restrict__ cursor,
                                                 int* __restrict__ csr, int E) {
    int e = blockIdx.x * 256 + threadIdx.x;
    if (e >= E) return;
    int pos = atomicAdd(&cursor[dst[e]], 1);
    csr[pos] = src[e];
}

// 3a. pack W into MFMA B-fragment order: Bp[(t*8+q)*64 + lane][i] =
//     W[k = q*32 + 8*(lane>>4) + i][n = t*16 + (lane&15)], bf16
__global__ __launch_bounds__(256) void k_packB(const float* __restrict__ Wb,
                                               const float* __restrict__ Wc,
                                               const float* __restrict__ cb,
                                               bf16* __restrict__ Bp) {
    int tid = blockIdx.x * 256 + threadIdx.x;
    if (tid >= NTILES * 8 * 64) return;
    int l = tid & 63;
    int q = (tid >> 6) & 7;
    int t = tid >> 9;
    int n = t * 16 + (l & 15);
    int k0 = q * 32 + (l >> 4) * 8;
    short out[8];
#pragma unroll
    for (int i = 0; i < 8; ++i) {
        int k = k0 + i;
        float v = (n < BFD) ? Wb[k * BFD + n] : Wc[k * NCOMB + (n - BFD)];
        unsigned u = __float_as_uint(v);
        out[i] = (short)((u + 0x7FFFu + ((u >> 16) & 1u)) >> 16);
    }
    *(sh8*)(Bp + (size_t)tid * 8) = *(sh8*)out;
    (void)cb;
}

// 3b. MFMA node GEMM, 64 rows/block, 4 waves (one 16-row M-subtile each).
//     Optionally fuses previous layer's BN-apply+ReLU+residual into staging.
template <typename TH, typename TW>
__global__ __launch_bounds__(256) void k_gemm_mfma(TH* __restrict__ h,
                                                   const bf16* __restrict__ Bp,
                                                   const float* __restrict__ cb,
                                                   bf16* __restrict__ bases,
                                                   TW* __restrict__ wco,
                                                   const bf16* __restrict__ convp,
                                                   const float* __restrict__ ss) {
    __shared__ unsigned ldsA[8192];  // 64 rows x 256 cols bf16, XOR-swizzled
    int tid = threadIdx.x;
    size_t blk = blockIdx.x;
    // ---- stage h -> bf16 LDS (+ fused apply_res of previous layer) ----
#pragma unroll 4
    for (int it = 0; it < 32; ++it) {
        int p = tid + it * 256;
        int row = p >> 7, cp = p & 127;       // cp = column pair
        size_t rg = blk * 64 + row;
        unsigned word = 0;
        if (rg < NNODES) {
            int c0 = cp * 2;
            float a0 = ldf(&h[rg * HIDC + c0]);
            float a1 = ldf(&h[rg * HIDC + c0 + 1]);
            if (convp) {
                float v0 = b2f(convp[rg * HIDC + c0]) * ss[c0] + ss[HIDC + c0];
                float v1 = b2f(convp[rg * HIDC + c0 + 1]) * ss[c0 + 1] + ss[HIDC + c0 + 1];
                a0 += fmaxf(v0, 0.f);
                a1 += fmaxf(v1, 0.f);
                stf(&h[rg * HIDC + c0], a0);
                stf(&h[rg * HIDC + c0 + 1], a1);
            }
            word = pack2bf(a0, a1);
        }
        ldsA[(row * 128 + cp) ^ ((row & 7) << 2)] = word;
    }
    __syncthreads();
    // ---- MFMA ----
    int w = tid >> 6, l = tid & 63;
    int r = 16 * w + (l & 15);
    sh8 af[8];
    const char* lb = (const char*)ldsA;
#pragma unroll
    for (int q = 0; q < 8; ++q) {
        int byte = (r * 512 + q * 64 + (l >> 4) * 16) ^ ((r & 7) << 4);
        af[q] = *(const sh8*)(lb + byte);
    }
    fx4 acc[NTILES];
#pragma unroll
    for (int t = 0; t < NTILES; ++t) acc[t] = (fx4){0.f, 0.f, 0.f, 0.f};
    const sh8* bp8 = (const sh8*)Bp;
#pragma unroll
    for (int t = 0; t < NTILES; ++t) {
#pragma unroll
        for (int q = 0; q < 8; ++q) {
            acc[t] = __builtin_amdgcn_mfma_f32_16x16x32_bf16(
                af[q], bp8[(t * 8 + q) * 64 + l], acc[t], 0, 0, 0);
        }
    }
    // ---- store: D row=(lane>>4)*4+j (+16w), col=lane&15 (+16t) ----
#pragma unroll
    for (int t = 0; t < NTILES; ++t) {
#pragma unroll
        for (int j = 0; j < 4; ++j) {
            int rl = 16 * w + (l >> 4) * 4 + j;
            size_t rg = blk * 64 + rl;
            if (rg >= NNODES) continue;
            if (t < 8) {
                int col = t * 16 + (l & 15);
                bases[rg * BFD + col] = f2b(acc[t][j]);
            } else {
                int col = (t - 8) * 16 + (l & 15);
                stf(&wco[rg * NCOMB + col], acc[t][j] + cb[col]);
            }
        }
    }
}

// 4. fused CSR aggregation + einsum. One wave per node (4 nodes/block).
template <typename TW>
__global__ __launch_bounds__(256) void k_agg(const int* __restrict__ rowptr,
                                             const int* __restrict__ csr,
                                             const unsigned* __restrict__ basesu,
                                             const TW* __restrict__ wco,
                                             const float* __restrict__ bias,
                                             bf16* __restrict__ conv) {
    __shared__ float agg[4][3][BFD];
    int wv = threadIdx.x >> 6;
    int lane = threadIdx.x & 63;
    int n = blockIdx.x * 4 + wv;
    int r0 = rowptr[n], r1 = rowptr[n + 1];
    float s0 = 0.f, s1 = 0.f, mx0 = -INFINITY, mx1 = -INFINITY;
    int e = r0;
    for (; e + 4 <= r1; e += 4) {
        int i0 = csr[e + 0] * 64, i1 = csr[e + 1] * 64;
        int i2 = csr[e + 2] * 64, i3 = csr[e + 3] * 64;
        unsigned v0 = basesu[i0 + lane], v1 = basesu[i1 + lane];
        unsigned v2 = basesu[i2 + lane], v3 = basesu[i3 + lane];
#define ACCV(v) { float lo = __uint_as_float((v) << 16);            \
                  float hi = __uint_as_float((v) & 0xFFFF0000u);    \
                  s0 += lo; s1 += hi;                               \
                  mx0 = fmaxf(mx0, lo); mx1 = fmaxf(mx1, hi); }
        ACCV(v0) ACCV(v1) ACCV(v2) ACCV(v3)
    }
    for (; e < r1; ++e) {
        unsigned v = basesu[csr[e] * 64 + lane];
        ACCV(v)
    }
#undef ACCV
    float inv = 1.0f / fmaxf((float)(r1 - r0), 1.0f);
    agg[wv][0][2 * lane] = s0;       agg[wv][0][2 * lane + 1] = s1;
    agg[wv][1][2 * lane] = s0 * inv; agg[wv][1][2 * lane + 1] = s1 * inv;
    agg[wv][2][2 * lane] = mx0;      agg[wv][2][2 * lane + 1] = mx1;
    __syncthreads();
    int c = threadIdx.x;
    int hh = c >> 5, d = c & 31;
    float bb = bias[c];
#pragma unroll
    for (int w2 = 0; w2 < 4; ++w2) {
        int n2 = blockIdx.x * 4 + w2;
        const TW* wp = &wco[(size_t)n2 * NCOMB + hh * 12];
        float a = 0.f;
#pragma unroll
        for (int b = 0; b < 4; ++b) {
            a += ldf(&wp[0 + b]) * agg[w2][0][b * 32 + d];
            a += ldf(&wp[4 + b]) * agg[w2][1][b * 32 + d];
            a += ldf(&wp[8 + b]) * agg[w2][2][b * 32 + d];
        }
        conv[(size_t)n2 * HIDC + c] = f2b(a + bb);
    }
}

// 5. BN stats over conv (bf16)
__global__ __launch_bounds__(256) void k_stats_bf(const bf16* __restrict__ conv,
                                                  float* __restrict__ sums, int rows,
                                                  int rpb) {
    int c = threadIdx.x;
    int r0 = blockIdx.x * rpb;
    int r1 = min(r0 + rpb, rows);
    float s = 0.f, s2 = 0.f;
    for (int r = r0; r < r1; ++r) {
        float v = b2f(conv[(size_t)r * HIDC + c]);
        s += v;
        s2 += v * v;
    }
    atomicAdd(&sums[c], s);
    atomicAdd(&sums[HIDC + c], s2);
}

// 6. BN finalize
template <int C>
__global__ void k_bnfin(const float* __restrict__ sums, const float* __restrict__ g,
                        const float* __restrict__ b, float nrows, float* __restrict__ ss) {
    int c = threadIdx.x;
    float mu = sums[c] / nrows;
    float var = sums[C + c] / nrows - mu * mu;
    float rstd = rsqrtf(fmaxf(var, 0.f) + EPSV);
    float sc = rstd * g[c];
    ss[c] = sc;
    ss[C + c] = b[c] - mu * sc;
}

// 7. BN apply + ReLU + residual into h (only needed after final layer)
template <typename TH>
__global__ __launch_bounds__(256) void k_apply_res(const bf16* __restrict__ conv,
                                                   const float* __restrict__ ss,
                                                   TH* __restrict__ h) {
    int n = blockIdx.x;
    int c = threadIdx.x;
    float v = b2f(conv[(size_t)n * HIDC + c]) * ss[c] + ss[HIDC + c];
    size_t i = (size_t)n * HIDC + c;
    stf(&h[i], ldf(&h[i]) + fmaxf(v, 0.f));
}

// 8. pooling: sorted batch -> register accumulate, flush at boundaries
template <typename TH>
__global__ __launch_bounds__(256) void k_pool(const TH* __restrict__ h,
                                              const int* __restrict__ batch,
                                              float* __restrict__ gs,
                                              float* __restrict__ cnt) {
    int c = threadIdx.x;
    int n0 = blockIdx.x * NPP;
    int end = min(n0 + NPP, NNODES);
    float acc = 0.f, ccnt = 0.f;
    int cur = batch[n0];
    for (int n = n0; n < end; ++n) {
        int b = batch[n];
        if (b != cur) {
            atomicAdd(&gs[(size_t)cur * HIDC + c], acc);
            if (c == 0) atomicAdd(&cnt[cur], ccnt);
            acc = 0.f; ccnt = 0.f; cur = b;
        }
        acc += ldf(&h[(size_t)n * HIDC + c]);
        ccnt += 1.f;
    }
    atomicAdd(&gs[(size_t)cur * HIDC + c], acc);
    if (c == 0) atomicAdd(&cnt[cur], ccnt);
}

__global__ __launch_bounds__(256) void k_pooldiv(float* __restrict__ gs,
                                                 const float* __restrict__ cnt) {
    int i = blockIdx.x * 256 + threadIdx.x;
    if (i >= NGR * HIDC) return;
    int ng = i >> 8;
    gs[i] = gs[i] / fmaxf(cnt[ng], 1.0f);
}

// 9. head row-GEMM
template <int K, int C>
__global__ void k_rowgemm(const float* __restrict__ in, const float* __restrict__ W,
                          float* __restrict__ out) {
    int r = blockIdx.x;
    __shared__ float rs[K];
    for (int i = threadIdx.x; i < K; i += C) rs[i] = in[r * K + i];
    __syncthreads();
    int c = threadIdx.x;
    float acc = 0.f;
    for (int k = 0; k < K; ++k) acc += rs[k] * W[k * C + c];
    out[r * C + c] = acc;
}

// 10. head BN stats
template <int C>
__global__ void k_stats(const float* __restrict__ a, int rows, int rpb,
                        float* __restrict__ sums) {
    int c = threadIdx.x;
    int r0 = blockIdx.x * rpb;
    int r1 = min(r0 + rpb, rows);
    float s = 0.f, s2 = 0.f;
    for (int r = r0; r < r1; ++r) {
        float v = a[r * C + c];
        s += v;
        s2 += v * v;
    }
    atomicAdd(&sums[c], s);
    atomicAdd(&sums[C + c], s2);
}

// 11. head BN apply + ReLU
template <int C>
__global__ void k_apply_relu(float* __restrict__ a, const float* __restrict__ ss, int rows) {
    int i = blockIdx.x * 256 + threadIdx.x;
    if (i >= rows * C) return;
    int c = i % C;
    float v = a[i] * ss[c] + ss[C + c];
    a[i] = fmaxf(v, 0.f);
}

// 12. final linear
__global__ __launch_bounds__(256) void k_final(const float* __restrict__ g2,
                                               const float* __restrict__ w3,
                                               const float* __restrict__ b3,
                                               float* __restrict__ out) {
    int r = blockIdx.x * 256 + threadIdx.x;
    if (r >= NGR) return;
    float acc = 0.f;
#pragma unroll
    for (int k = 0; k < 64; ++k) acc += g2[r * 64 + k] * w3[k];
    out[r] = acc + b3[0];
}

static inline size_t alignup(size_t v) { return (v + 255) & ~(size_t)255; }

template <typename TH, typename TW>
static size_t carve_need(int E) {
    size_t off = 0;
    off = alignup(off + (size_t)NNODES * HIDC * sizeof(TH));   // h
    off = alignup(off + (size_t)NNODES * BFD * 2);             // bases bf16
    off = alignup(off + (size_t)NNODES * NCOMB * sizeof(TW));  // wco
    off = alignup(off + (size_t)NNODES * HIDC * 2);            // conv bf16
    off = alignup(off + (size_t)(NNODES + 1) * 4);             // rowptr
    off = alignup(off + (size_t)NNODES * 4);                   // cursor
    off = alignup(off + (size_t)E * 4);                        // csr
    off = alignup(off + 2 * HIDC * 4);                         // sums
    off = alignup(off + 2 * HIDC * 4);                         // ss
    off = alignup(off + 256 * 4);                              // btot
    off = alignup(off + 256 * 4);                              // boff
    off = alignup(off + (size_t)NTILES * 8 * 64 * 8 * 2);      // Bp
    return off;  // pool/head alias conv region (6.8 MB < 51.2 MB)
}

template <typename TH, typename TW>
static void run_all(const int* x, const int* esrc, const int* edst, const int* batch,
                    const float* emb, const float* basesW, const float* combW,
                    const float* combB, const float* convB, const float* bnG,
                    const float* bnB, const float* w1, const float* bn1g,
                    const float* bn1b, const float* w2, const float* bn2g,
                    const float* bn2b, const float* w3, const float* b3, int E,
                    float* out, char* base, hipStream_t stream) {
    size_t off = 0;
    TH* h = (TH*)(base + off);       off = alignup(off + (size_t)NNODES * HIDC * sizeof(TH));
    bf16* bases = (bf16*)(base + off); off = alignup(off + (size_t)NNODES * BFD * 2);
    TW* wco = (TW*)(base + off);     off = alignup(off + (size_t)NNODES * NCOMB * sizeof(TW));
    size_t o_conv = off;
    bf16* conv = (bf16*)(base + off); off = alignup(off + (size_t)NNODES * HIDC * 2);
    int* rowptr = (int*)(base + off); off = alignup(off + (size_t)(NNODES + 1) * 4);
    int* cursor = (int*)(base + off); off = alignup(off + (size_t)NNODES * 4);
    int* csr = (int*)(base + off);    off = alignup(off + (size_t)E * 4);
    float* sums = (float*)(base + off); off = alignup(off + 2 * HIDC * 4);
    float* ss = (float*)(base + off);   off = alignup(off + 2 * HIDC * 4);
    int* btot = (int*)(base + off);     off = alignup(off + 256 * 4);
    int* boff = (int*)(base + off);     off = alignup(off + 256 * 4);
    bf16* Bp = (bf16*)(base + off);     off = alignup(off + (size_t)NTILES * 8 * 64 * 8 * 2);
    // pool/head buffers alias conv region (dead after layers)
    size_t po = o_conv;
    float* gs = (float*)(base + po);  po = alignup(po + (size_t)NGR * HIDC * 4);
    float* cnt = (float*)(base + po); po = alignup(po + (size_t)NGR * 4);
    float* r1 = (float*)(base + po);  po = alignup(po + (size_t)NGR * 128 * 4);
    float* r2 = (float*)(base + po);  po = alignup(po + (size_t)NGR * 64 * 4);

    const int NB = (NNODES + SCHUNK - 1) / SCHUNK;  // 98
    const int GEMMBLK = (NNODES + 63) / 64;         // 1563

    // once: embeddings + CSR build
    k_atom<TH><<<NNODES, 256, 0, stream>>>(x, emb, h);
    hipMemsetAsync(cursor, 0, (size_t)NNODES * 4, stream);
    k_hist<<<(E + 255) / 256, 256, 0, stream>>>(edst, cursor, E);
    k_scansum<<<NB, 256, 0, stream>>>(cursor, btot, NNODES);
    k_scansmall<<<1, 64, 0, stream>>>(btot, boff, NB);
    k_scanapply<<<NB, 256, 0, stream>>>(cursor, boff, rowptr, NNODES);
    k_copy<<<(NNODES + 255) / 256, 256, 0, stream>>>(rowptr, cursor, NNODES);
    k_scatter<<<(E + 255) / 256, 256, 0, stream>>>(esrc, edst, cursor, csr, E);

    for (int l = 0; l < LAYERSN; ++l) {
        hipMemsetAsync(sums, 0, 2 * HIDC * 4, stream);
        k_packB<<<28, 256, 0, stream>>>(basesW + (size_t)l * HIDC * BFD,
                                        combW + (size_t)l * HIDC * NCOMB,
                                        combB + (size_t)l * NCOMB, Bp);
        // fuse previous layer's BN-apply+ReLU+residual into staging (l>0)
        k_gemm_mfma<TH, TW><<<GEMMBLK, 256, 0, stream>>>(
            h, Bp, combB + (size_t)l * NCOMB, bases, wco,
            (l > 0) ? conv : (const bf16*)nullptr, ss);
        k_agg<TW><<<NNODES / 4, 256, 0, stream>>>(rowptr, csr, (const unsigned*)bases,
                                                  wco, convB + (size_t)l * HIDC, conv);
        k_stats_bf<<<(NNODES + 255) / 256, 256, 0, stream>>>(conv, sums, NNODES, 256);
        k_bnfin<HIDC><<<1, HIDC, 0, stream>>>(sums, bnG + (size_t)l * HIDC,
                                              bnB + (size_t)l * HIDC, (float)NNODES, ss);
    }
    // final layer's apply (no following GEMM to fuse into)
    k_apply_res<TH><<<NNODES, 256, 0, stream>>>(conv, ss, h);

    hipMemsetAsync(gs, 0, (size_t)NGR * HIDC * 4, stream);
    hipMemsetAsync(cnt, 0, (size_t)NGR * 4, stream);
    k_pool<TH><<<(NNODES + NPP - 1) / NPP, 256, 0, stream>>>(h, batch, gs, cnt);
    k_pooldiv<<<(NGR * HIDC + 255) / 256, 256, 0, stream>>>(gs, cnt);

    k_rowgemm<256, 128><<<NGR, 128, 0, stream>>>(gs, w1, r1);
    hipMemsetAsync(sums, 0, 2 * 128 * 4, stream);
    k_stats<128><<<(NGR + 15) / 16, 128, 0, stream>>>(r1, NGR, 16, sums);
    k_bnfin<128><<<1, 128, 0, stream>>>(sums, bn1g, bn1b, (float)NGR, ss);
    k_apply_relu<128><<<(NGR * 128 + 255) / 256, 256, 0, stream>>>(r1, ss, NGR);

    k_rowgemm<128, 64><<<NGR, 64, 0, stream>>>(r1, w2, r2);
    hipMemsetAsync(sums, 0, 2 * 64 * 4, stream);
    k_stats<64><<<(NGR + 31) / 32, 64, 0, stream>>>(r2, NGR, 32, sums);
    k_bnfin<64><<<1, 64, 0, stream>>>(sums, bn2g, bn2b, (float)NGR, ss);
    k_apply_relu<64><<<(NGR * 64 + 255) / 256, 256, 0, stream>>>(r2, ss, NGR);

    k_final<<<(NGR + 255) / 256, 256, 0, stream>>>(r2, w3, b3, out);
}

extern "C" void kernel_launch(void* const* d_in, const int* in_sizes, int n_in,
                              void* d_out, int out_size, void* d_ws, size_t ws_size,
                              hipStream_t stream) {
    const int* x        = (const int*)d_in[0];
    const int* esrc     = (const int*)d_in[1];
    const int* edst     = (const int*)d_in[2];
    const int* batch    = (const int*)d_in[3];
    const float* emb    = (const float*)d_in[4];
    const float* basesW = (const float*)d_in[5];
    const float* combW  = (const float*)d_in[6];
    const float* combB  = (const float*)d_in[7];
    const float* convB  = (const float*)d_in[8];
    const float* bnG    = (const float*)d_in[9];
    const float* bnB    = (const float*)d_in[10];
    const float* w1     = (const float*)d_in[11];
    const float* bn1g   = (const float*)d_in[12];
    const float* bn1b   = (const float*)d_in[13];
    const float* w2     = (const float*)d_in[14];
    const float* bn2g   = (const float*)d_in[15];
    const float* bn2b   = (const float*)d_in[16];
    const float* w3     = (const float*)d_in[17];
    const float* b3     = (const float*)d_in[18];
    const int E = in_sizes[1];

    size_t need_full    = carve_need<float, float>(E);
    size_t need_compact = carve_need<bf16, bf16>(E);

    if (ws_size >= need_full) {
        run_all<float, float>(x, esrc, edst, batch, emb, basesW, combW, combB, convB,
                              bnG, bnB, w1, bn1g, bn1b, w2, bn2g, bn2b, w3, b3, E,
                              (float*)d_out, (char*)d_ws, stream);
    } else if (ws_size >= need_compact) {
        run_all<bf16, bf16>(x, esrc, edst, batch, emb, basesW, combW, combB, convB,
                            bnG, bnB, w1, bn1g, bn1b, w2, bn2g, bn2b, w3, b3, E,
                            (float*)d_out, (char*)d_ws, stream);
    } else {
        k_sentinel<<<(out_size + 255) / 256, 256, 0, stream>>>(
            (float*)d_out, out_size, (float)(ws_size >> 20));
    }
}

// Round 9
// 1499.367 us; speedup vs baseline: 2.3863x; 1.0262x over previous
//
#include <hip/hip_runtime.h>
#include <hip/hip_bf16.h>

#define NNODES 100000
#define HIDC 256
#define NFEAT 9
#define VOCABS 128
#define BFD 128        // bases output dim
#define NCOMB 96       // heads*bases*aggs
#define NGR 5000
#define LAYERSN 4
#define EPSV 1e-5f
#define SCHUNK 1024    // scan chunk
#define NPP 16         // nodes per block in pooling
#define NTILES 14      // 224/16 output tiles (8 bases + 6 comb)
#define AGGBLK 2048    // agg grid (8192 waves = 32 waves/CU)
#define AGGW (AGGBLK * 4)
#define PBL (NTILES * 8 * 64)   // B fragments per layer

typedef __hip_bfloat16 bf16;
typedef __attribute__((ext_vector_type(8))) short sh8;   // 8 bf16 (4 VGPRs)
typedef __attribute__((ext_vector_type(4))) float fx4;   // MFMA acc

__device__ __forceinline__ float b2f(bf16 v) { return __bfloat162float(v); }
__device__ __forceinline__ bf16 f2b(float v) { return __float2bfloat16(v); }
__device__ __forceinline__ float ldf(const float* p) { return *p; }
__device__ __forceinline__ float ldf(const bf16* p) { return b2f(*p); }
__device__ __forceinline__ void stf(float* p, float v) { *p = v; }
__device__ __forceinline__ void stf(bf16* p, float v) { *p = f2b(v); }

__device__ __forceinline__ unsigned pack2bf(float a, float b) {
    unsigned ua = __float_as_uint(a), ub = __float_as_uint(b);
    ua = (ua + 0x7FFFu + ((ua >> 16) & 1u)) >> 16;
    ub = (ub + 0x7FFFu + ((ub >> 16) & 1u)) >> 16;
    return ua | (ub << 16);
}

// 0. sentinel
__global__ __launch_bounds__(256) void k_sentinel(float* out, int n, float val) {
    int i = blockIdx.x * 256 + threadIdx.x;
    if (i < n) out[i] = val;
}

// 1. AtomEncoder
template <typename TH>
__global__ __launch_bounds__(256) void k_atom(const int* __restrict__ x,
                                              const float* __restrict__ emb,
                                              TH* __restrict__ h) {
    int n = blockIdx.x;
    __shared__ int xs[NFEAT];
    if (threadIdx.x < NFEAT) xs[threadIdx.x] = x[n * NFEAT + threadIdx.x];
    __syncthreads();
    int c = threadIdx.x;
    float acc = 0.f;
#pragma unroll
    for (int f = 0; f < NFEAT; ++f)
        acc += emb[(f * VOCABS + xs[f]) * HIDC + c];
    stf(&h[(size_t)n * HIDC + c], acc);
}

// 2a-2d: CSR build
__global__ __launch_bounds__(256) void k_hist(const int* __restrict__ dst,
                                              int* __restrict__ counts, int E) {
    int e = blockIdx.x * 256 + threadIdx.x;
    if (e < E) atomicAdd(&counts[dst[e]], 1);
}

__global__ __launch_bounds__(256) void k_scansum(const int* __restrict__ counts,
                                                 int* __restrict__ btot, int n) {
    __shared__ int sh[256];
    int b = blockIdx.x, t = threadIdx.x;
    int base = b * SCHUNK;
    int s = 0;
#pragma unroll
    for (int k = 0; k < 4; ++k) {
        int i = base + t + k * 256;
        if (i < n) s += counts[i];
    }
    sh[t] = s;
    __syncthreads();
    for (int st = 128; st > 0; st >>= 1) {
        if (t < st) sh[t] += sh[t + st];
        __syncthreads();
    }
    if (t == 0) btot[b] = sh[0];
}

__global__ void k_scansmall(const int* __restrict__ btot, int* __restrict__ boff, int nb) {
    if (threadIdx.x == 0 && blockIdx.x == 0) {
        int a = 0;
        for (int i = 0; i < nb; ++i) { boff[i] = a; a += btot[i]; }
    }
}

// 2b-3. per-chunk scan -> rowptr AND cursor (k_copy merged in)
__global__ __launch_bounds__(256) void k_scanapply(const int* __restrict__ counts,
                                                   const int* __restrict__ boff,
                                                   int* __restrict__ rowptr,
                                                   int* __restrict__ cursor, int n) {
    __shared__ int sh[256];
    int b = blockIdx.x, t = threadIdx.x;
    int base = b * SCHUNK + t * 4;
    int c0 = (base + 0 < n) ? counts[base + 0] : 0;
    int c1 = (base + 1 < n) ? counts[base + 1] : 0;
    int c2 = (base + 2 < n) ? counts[base + 2] : 0;
    int c3 = (base + 3 < n) ? counts[base + 3] : 0;
    int s0 = c0, s1 = s0 + c1, s2 = s1 + c2, s3 = s2 + c3;
    sh[t] = s3;
    __syncthreads();
    for (int st = 1; st < 256; st <<= 1) {
        int v = (t >= st) ? sh[t - st] : 0;
        __syncthreads();
        sh[t] += v;
        __syncthreads();
    }
    int excl = sh[t] - s3 + boff[b];
    if (base + 0 < n) { rowptr[base + 1] = excl + s0; cursor[base + 0] = excl; }
    if (base + 1 < n) { rowptr[base + 2] = excl + s1; cursor[base + 1] = excl + s0; }
    if (base + 2 < n) { rowptr[base + 3] = excl + s2; cursor[base + 2] = excl + s1; }
    if (base + 3 < n) { rowptr[base + 4] = excl + s3; cursor[base + 3] = excl + s2; }
    if (b == 0 && t == 0) rowptr[0] = 0;
}

__global__ __launch_bounds__(256) void k_scatter(const int* __restrict__ src,
                                                 const int* __restrict__ dst,
                                                 int* __restrict__ cursor,
                                                 int* __restrict__ csr, int E) {
    int e = blockIdx.x * 256 + threadIdx.x;
    if (e >= E) return;
    int pos = atomicAdd(&cursor[dst[e]], 1);
    csr[pos] = src[e];
}

// 3a. pack W of ALL layers into MFMA B-fragment order
__global__ __launch_bounds__(256) void k_packB4(const float* __restrict__ basesW,
                                                const float* __restrict__ combW,
                                                bf16* __restrict__ Bp4) {
    int tid = blockIdx.x * 256 + threadIdx.x;
    if (tid >= LAYERSN * PBL) return;
    int layer = tid / PBL;
    int rem = tid % PBL;
    int l = rem & 63;
    int q = (rem >> 6) & 7;
    int t = rem >> 9;
    int n = t * 16 + (l & 15);
    int k0 = q * 32 + (l >> 4) * 8;
    const float* Wb = basesW + (size_t)layer * HIDC * BFD;
    const float* Wc = combW + (size_t)layer * HIDC * NCOMB;
    short out[8];
#pragma unroll
    for (int i = 0; i < 8; ++i) {
        int k = k0 + i;
        float v = (n < BFD) ? Wb[k * BFD + n] : Wc[k * NCOMB + (n - BFD)];
        unsigned u = __float_as_uint(v);
        out[i] = (short)((u + 0x7FFFu + ((u >> 16) & 1u)) >> 16);
    }
    *(sh8*)(Bp4 + (size_t)tid * 8) = *(sh8*)out;
}

// 3b. MFMA node GEMM (64 rows/block, 4 waves) + optional fused prev-layer apply
template <typename TH, typename TW>
__global__ __launch_bounds__(256) void k_gemm_mfma(TH* __restrict__ h,
                                                   const bf16* __restrict__ Bp,
                                                   const float* __restrict__ cb,
                                                   bf16* __restrict__ bases,
                                                   TW* __restrict__ wco,
                                                   const bf16* __restrict__ convp,
                                                   const float* __restrict__ ss) {
    __shared__ unsigned ldsA[8192];
    int tid = threadIdx.x;
    size_t blk = blockIdx.x;
#pragma unroll 4
    for (int it = 0; it < 32; ++it) {
        int p = tid + it * 256;
        int row = p >> 7, cp = p & 127;
        size_t rg = blk * 64 + row;
        unsigned word = 0;
        if (rg < NNODES) {
            int c0 = cp * 2;
            float a0 = ldf(&h[rg * HIDC + c0]);
            float a1 = ldf(&h[rg * HIDC + c0 + 1]);
            if (convp) {
                float v0 = b2f(convp[rg * HIDC + c0]) * ss[c0] + ss[HIDC + c0];
                float v1 = b2f(convp[rg * HIDC + c0 + 1]) * ss[c0 + 1] + ss[HIDC + c0 + 1];
                a0 += fmaxf(v0, 0.f);
                a1 += fmaxf(v1, 0.f);
                stf(&h[rg * HIDC + c0], a0);
                stf(&h[rg * HIDC + c0 + 1], a1);
            }
            word = pack2bf(a0, a1);
        }
        ldsA[(row * 128 + cp) ^ ((row & 7) << 2)] = word;
    }
    __syncthreads();
    int w = tid >> 6, l = tid & 63;
    int r = 16 * w + (l & 15);
    sh8 af[8];
    const char* lb = (const char*)ldsA;
#pragma unroll
    for (int q = 0; q < 8; ++q) {
        int byte = (r * 512 + q * 64 + (l >> 4) * 16) ^ ((r & 7) << 4);
        af[q] = *(const sh8*)(lb + byte);
    }
    fx4 acc[NTILES];
#pragma unroll
    for (int t = 0; t < NTILES; ++t) acc[t] = (fx4){0.f, 0.f, 0.f, 0.f};
    const sh8* bp8 = (const sh8*)Bp;
#pragma unroll
    for (int t = 0; t < NTILES; ++t) {
#pragma unroll
        for (int q = 0; q < 8; ++q) {
            acc[t] = __builtin_amdgcn_mfma_f32_16x16x32_bf16(
                af[q], bp8[(t * 8 + q) * 64 + l], acc[t], 0, 0, 0);
        }
    }
#pragma unroll
    for (int t = 0; t < NTILES; ++t) {
#pragma unroll
        for (int j = 0; j < 4; ++j) {
            int rl = 16 * w + (l >> 4) * 4 + j;
            size_t rg = blk * 64 + rl;
            if (rg >= NNODES) continue;
            if (t < 8) {
                int col = t * 16 + (l & 15);
                bases[rg * BFD + col] = f2b(acc[t][j]);
            } else {
                int col = (t - 8) * 16 + (l & 15);
                stf(&wco[rg * NCOMB + col], acc[t][j] + cb[col]);
            }
        }
    }
}

// 4. CSR aggregation + einsum + fused BN-stat partials.
//    Grid-stride by wave; 8B/lane gathers (2 edges per load across the wave).
template <typename TW>
__global__ __launch_bounds__(256) void k_agg(const int* __restrict__ rowptr,
                                             const int* __restrict__ csr,
                                             const uint2* __restrict__ b2,
                                             const TW* __restrict__ wco,
                                             const float* __restrict__ bias,
                                             bf16* __restrict__ conv,
                                             float* __restrict__ partials) {
    __shared__ float agg[4][3][BFD];
    __shared__ int nid[4];
    int tid = threadIdx.x;
    int wv = tid >> 6, lane = tid & 63;
    int cl = lane & 31;
    bool loh = lane < 32;
    int c = tid, hh = c >> 5, d = c & 31;
    float bb = bias[c];
    float st_s = 0.f, st_s2 = 0.f;
    const int ITERS = (NNODES + AGGW - 1) / AGGW;
    int n = blockIdx.x * 4 + wv;
    for (int it = 0; it < ITERS; ++it, n += AGGW) {
        if (n < NNODES) {
            if (lane == 0) nid[wv] = n;
            int r0 = rowptr[n], r1 = rowptr[n + 1];
            float s0 = 0.f, s1 = 0.f, s2 = 0.f, s3 = 0.f;
            float m0 = -INFINITY, m1 = -INFINITY, m2 = -INFINITY, m3 = -INFINITY;
            int e = r0;
#define ACCU2(v) { float f0 = __uint_as_float((v).x << 16);            \
                   float f1 = __uint_as_float((v).x & 0xFFFF0000u);    \
                   float f2 = __uint_as_float((v).y << 16);            \
                   float f3 = __uint_as_float((v).y & 0xFFFF0000u);    \
                   s0 += f0; s1 += f1; s2 += f2; s3 += f3;             \
                   m0 = fmaxf(m0, f0); m1 = fmaxf(m1, f1);             \
                   m2 = fmaxf(m2, f2); m3 = fmaxf(m3, f3); }
            for (; e + 4 <= r1; e += 4) {
                int sa = loh ? csr[e + 0] : csr[e + 1];
                int sb = loh ? csr[e + 2] : csr[e + 3];
                uint2 va = b2[(size_t)sa * 32 + cl];
                uint2 vb = b2[(size_t)sb * 32 + cl];
                ACCU2(va) ACCU2(vb)
            }
            for (; e + 2 <= r1; e += 2) {
                int sa = loh ? csr[e + 0] : csr[e + 1];
                uint2 va = b2[(size_t)sa * 32 + cl];
                ACCU2(va)
            }
            if (e < r1 && loh) {
                uint2 va = b2[(size_t)csr[e] * 32 + cl];
                ACCU2(va)
            }
#undef ACCU2
            // combine the two half-wave accumulators
            float t0 = s0 + __shfl_xor(s0, 32);
            float t1 = s1 + __shfl_xor(s1, 32);
            float t2 = s2 + __shfl_xor(s2, 32);
            float t3 = s3 + __shfl_xor(s3, 32);
            float x0 = fmaxf(m0, __shfl_xor(m0, 32));
            float x1 = fmaxf(m1, __shfl_xor(m1, 32));
            float x2 = fmaxf(m2, __shfl_xor(m2, 32));
            float x3 = fmaxf(m3, __shfl_xor(m3, 32));
            if (loh) {
                float inv = 1.0f / (float)(r1 - r0);
                int cc = 4 * cl;
                agg[wv][0][cc + 0] = t0; agg[wv][1][cc + 0] = t0 * inv; agg[wv][2][cc + 0] = x0;
                agg[wv][0][cc + 1] = t1; agg[wv][1][cc + 1] = t1 * inv; agg[wv][2][cc + 1] = x1;
                agg[wv][0][cc + 2] = t2; agg[wv][1][cc + 2] = t2 * inv; agg[wv][2][cc + 2] = x2;
                agg[wv][0][cc + 3] = t3; agg[wv][1][cc + 3] = t3 * inv; agg[wv][2][cc + 3] = x3;
            }
        } else if (lane == 0) {
            nid[wv] = -1;
        }
        __syncthreads();
#pragma unroll
        for (int w2 = 0; w2 < 4; ++w2) {
            int n2 = nid[w2];
            if (n2 < 0) continue;
            const TW* wp = &wco[(size_t)n2 * NCOMB + hh * 12];
            float a = 0.f;
#pragma unroll
            for (int b = 0; b < 4; ++b) {
                a += ldf(&wp[0 + b]) * agg[w2][0][b * 32 + d];
                a += ldf(&wp[4 + b]) * agg[w2][1][b * 32 + d];
                a += ldf(&wp[8 + b]) * agg[w2][2][b * 32 + d];
            }
            a += bb;
            conv[(size_t)n2 * HIDC + c] = f2b(a);
            st_s += a;
            st_s2 += a * a;
        }
        __syncthreads();
    }
    partials[(size_t)blockIdx.x * 512 + c] = st_s;
    partials[(size_t)blockIdx.x * 512 + 256 + c] = st_s2;
}

// 4b. reduce partials -> sums[512]
__global__ __launch_bounds__(256) void k_redstats(const float* __restrict__ partials,
                                                  float* __restrict__ sums) {
    int g = blockIdx.x * 256 + threadIdx.x;   // 16 blocks -> 4096 threads
    int j = g & 511;
    int chunk = g >> 9;                        // 0..7
    float s = 0.f;
    for (int pb = chunk * 256; pb < (chunk + 1) * 256; ++pb)
        s += partials[(size_t)pb * 512 + j];
    atomicAdd(&sums[j], s);
}

// 6. BN finalize
template <int C>
__global__ void k_bnfin(const float* __restrict__ sums, const float* __restrict__ g,
                        const float* __restrict__ b, float nrows, float* __restrict__ ss) {
    int c = threadIdx.x;
    float mu = sums[c] / nrows;
    float var = sums[C + c] / nrows - mu * mu;
    float rstd = rsqrtf(fmaxf(var, 0.f) + EPSV);
    float sc = rstd * g[c];
    ss[c] = sc;
    ss[C + c] = b[c] - mu * sc;
}

// 7. BN apply + ReLU + residual into h (final layer only)
template <typename TH>
__global__ __launch_bounds__(256) void k_apply_res(const bf16* __restrict__ conv,
                                                   const float* __restrict__ ss,
                                                   TH* __restrict__ h) {
    int n = blockIdx.x;
    int c = threadIdx.x;
    float v = b2f(conv[(size_t)n * HIDC + c]) * ss[c] + ss[HIDC + c];
    size_t i = (size_t)n * HIDC + c;
    stf(&h[i], ldf(&h[i]) + fmaxf(v, 0.f));
}

// 8. pooling (sorted batch)
template <typename TH>
__global__ __launch_bounds__(256) void k_pool(const TH* __restrict__ h,
                                              const int* __restrict__ batch,
                                              float* __restrict__ gs,
                                              float* __restrict__ cnt) {
    int c = threadIdx.x;
    int n0 = blockIdx.x * NPP;
    int end = min(n0 + NPP, NNODES);
    float acc = 0.f, ccnt = 0.f;
    int cur = batch[n0];
    for (int n = n0; n < end; ++n) {
        int b = batch[n];
        if (b != cur) {
            atomicAdd(&gs[(size_t)cur * HIDC + c], acc);
            if (c == 0) atomicAdd(&cnt[cur], ccnt);
            acc = 0.f; ccnt = 0.f; cur = b;
        }
        acc += ldf(&h[(size_t)n * HIDC + c]);
        ccnt += 1.f;
    }
    atomicAdd(&gs[(size_t)cur * HIDC + c], acc);
    if (c == 0) atomicAdd(&cnt[cur], ccnt);
}

__global__ __launch_bounds__(256) void k_pooldiv(float* __restrict__ gs,
                                                 const float* __restrict__ cnt) {
    int i = blockIdx.x * 256 + threadIdx.x;
    if (i >= NGR * HIDC) return;
    int ng = i >> 8;
    gs[i] = gs[i] / fmaxf(cnt[ng], 1.0f);
}

// 9. head row-GEMM
template <int K, int C>
__global__ void k_rowgemm(const float* __restrict__ in, const float* __restrict__ W,
                          float* __restrict__ out) {
    int r = blockIdx.x;
    __shared__ float rs[K];
    for (int i = threadIdx.x; i < K; i += C) rs[i] = in[r * K + i];
    __syncthreads();
    int c = threadIdx.x;
    float acc = 0.f;
    for (int k = 0; k < K; ++k) acc += rs[k] * W[k * C + c];
    out[r * C + c] = acc;
}

// 10. head BN stats
template <int C>
__global__ void k_stats(const float* __restrict__ a, int rows, int rpb,
                        float* __restrict__ sums) {
    int c = threadIdx.x;
    int r0 = blockIdx.x * rpb;
    int r1 = min(r0 + rpb, rows);
    float s = 0.f, s2 = 0.f;
    for (int r = r0; r < r1; ++r) {
        float v = a[r * C + c];
        s += v;
        s2 += v * v;
    }
    atomicAdd(&sums[c], s);
    atomicAdd(&sums[C + c], s2);
}

// 11. head BN apply + ReLU
template <int C>
__global__ void k_apply_relu(float* __restrict__ a, const float* __restrict__ ss, int rows) {
    int i = blockIdx.x * 256 + threadIdx.x;
    if (i >= rows * C) return;
    int c = i % C;
    float v = a[i] * ss[c] + ss[C + c];
    a[i] = fmaxf(v, 0.f);
}

// 12. final linear
__global__ __launch_bounds__(256) void k_final(const float* __restrict__ g2,
                                               const float* __restrict__ w3,
                                               const float* __restrict__ b3,
                                               float* __restrict__ out) {
    int r = blockIdx.x * 256 + threadIdx.x;
    if (r >= NGR) return;
    float acc = 0.f;
#pragma unroll
    for (int k = 0; k < 64; ++k) acc += g2[r * 64 + k] * w3[k];
    out[r] = acc + b3[0];
}

static inline size_t alignup(size_t v) { return (v + 255) & ~(size_t)255; }

template <typename TH, typename TW>
static size_t carve_need(int E) {
    size_t off = 0;
    off = alignup(off + (size_t)NNODES * HIDC * sizeof(TH));   // h
    off = alignup(off + (size_t)NNODES * BFD * 2);             // bases bf16
    off = alignup(off + (size_t)NNODES * NCOMB * sizeof(TW));  // wco
    off = alignup(off + (size_t)NNODES * HIDC * 2);            // conv bf16
    off = alignup(off + (size_t)(NNODES + 1) * 4);             // rowptr
    off = alignup(off + (size_t)NNODES * 4);                   // cursor
    off = alignup(off + (size_t)E * 4);                        // csr
    off = alignup(off + 2 * HIDC * 4);                         // sums
    off = alignup(off + 2 * HIDC * 4);                         // ss
    off = alignup(off + 256 * 4);                              // btot
    off = alignup(off + 256 * 4);                              // boff
    off = alignup(off + (size_t)LAYERSN * PBL * 8 * 2);        // Bp4
    off = alignup(off + (size_t)AGGBLK * 512 * 4);             // partials
    return off;  // pool/head alias conv region (6.8 MB < 51.2 MB)
}

template <typename TH, typename TW>
static void run_all(const int* x, const int* esrc, const int* edst, const int* batch,
                    const float* emb, const float* basesW, const float* combW,
                    const float* combB, const float* convB, const float* bnG,
                    const float* bnB, const float* w1, const float* bn1g,
                    const float* bn1b, const float* w2, const float* bn2g,
                    const float* bn2b, const float* w3, const float* b3, int E,
                    float* out, char* base, hipStream_t stream) {
    size_t off = 0;
    TH* h = (TH*)(base + off);       off = alignup(off + (size_t)NNODES * HIDC * sizeof(TH));
    bf16* bases = (bf16*)(base + off); off = alignup(off + (size_t)NNODES * BFD * 2);
    TW* wco = (TW*)(base + off);     off = alignup(off + (size_t)NNODES * NCOMB * sizeof(TW));
    size_t o_conv = off;
    bf16* conv = (bf16*)(base + off); off = alignup(off + (size_t)NNODES * HIDC * 2);
    int* rowptr = (int*)(base + off); off = alignup(off + (size_t)(NNODES + 1) * 4);
    int* cursor = (int*)(base + off); off = alignup(off + (size_t)NNODES * 4);
    int* csr = (int*)(base + off);    off = alignup(off + (size_t)E * 4);
    float* sums = (float*)(base + off); off = alignup(off + 2 * HIDC * 4);
    float* ss = (float*)(base + off);   off = alignup(off + 2 * HIDC * 4);
    int* btot = (int*)(base + off);     off = alignup(off + 256 * 4);
    int* boff = (int*)(base + off);     off = alignup(off + 256 * 4);
    bf16* Bp4 = (bf16*)(base + off);    off = alignup(off + (size_t)LAYERSN * PBL * 8 * 2);
    float* partials = (float*)(base + off); off = alignup(off + (size_t)AGGBLK * 512 * 4);
    size_t po = o_conv;
    float* gs = (float*)(base + po);  po = alignup(po + (size_t)NGR * HIDC * 4);
    float* cnt = (float*)(base + po); po = alignup(po + (size_t)NGR * 4);
    float* r1 = (float*)(base + po);  po = alignup(po + (size_t)NGR * 128 * 4);
    float* r2 = (float*)(base + po);  po = alignup(po + (size_t)NGR * 64 * 4);

    const int NB = (NNODES + SCHUNK - 1) / SCHUNK;  // 98
    const int GEMMBLK = (NNODES + 63) / 64;         // 1563

    // once: embeddings + CSR build + all-layer weight pack
    k_atom<TH><<<NNODES, 256, 0, stream>>>(x, emb, h);
    k_packB4<<<(LAYERSN * PBL + 255) / 256, 256, 0, stream>>>(basesW, combW, Bp4);
    hipMemsetAsync(cursor, 0, (size_t)NNODES * 4, stream);
    k_hist<<<(E + 255) / 256, 256, 0, stream>>>(edst, cursor, E);
    k_scansum<<<NB, 256, 0, stream>>>(cursor, btot, NNODES);
    k_scansmall<<<1, 64, 0, stream>>>(btot, boff, NB);
    k_scanapply<<<NB, 256, 0, stream>>>(cursor, boff, rowptr, cursor, NNODES);
    k_scatter<<<(E + 255) / 256, 256, 0, stream>>>(esrc, edst, cursor, csr, E);

    for (int l = 0; l < LAYERSN; ++l) {
        hipMemsetAsync(sums, 0, 2 * HIDC * 4, stream);
        k_gemm_mfma<TH, TW><<<GEMMBLK, 256, 0, stream>>>(
            h, Bp4 + (size_t)l * PBL * 8, combB + (size_t)l * NCOMB, bases, wco,
            (l > 0) ? conv : (const bf16*)nullptr, ss);
        k_agg<TW><<<AGGBLK, 256, 0, stream>>>(rowptr, csr, (const uint2*)bases,
                                              wco, convB + (size_t)l * HIDC, conv,
                                              partials);
        k_redstats<<<16, 256, 0, stream>>>(partials, sums);
        k_bnfin<HIDC><<<1, HIDC, 0, stream>>>(sums, bnG + (size_t)l * HIDC,
                                              bnB + (size_t)l * HIDC, (float)NNODES, ss);
    }
    k_apply_res<TH><<<NNODES, 256, 0, stream>>>(conv, ss, h);

    hipMemsetAsync(gs, 0, (size_t)NGR * HIDC * 4, stream);
    hipMemsetAsync(cnt, 0, (size_t)NGR * 4, stream);
    k_pool<TH><<<(NNODES + NPP - 1) / NPP, 256, 0, stream>>>(h, batch, gs, cnt);
    k_pooldiv<<<(NGR * HIDC + 255) / 256, 256, 0, stream>>>(gs, cnt);

    k_rowgemm<256, 128><<<NGR, 128, 0, stream>>>(gs, w1, r1);
    hipMemsetAsync(sums, 0, 2 * 128 * 4, stream);
    k_stats<128><<<(NGR + 15) / 16, 128, 0, stream>>>(r1, NGR, 16, sums);
    k_bnfin<128><<<1, 128, 0, stream>>>(sums, bn1g, bn1b, (float)NGR, ss);
    k_apply_relu<128><<<(NGR * 128 + 255) / 256, 256, 0, stream>>>(r1, ss, NGR);

    k_rowgemm<128, 64><<<NGR, 64, 0, stream>>>(r1, w2, r2);
    hipMemsetAsync(sums, 0, 2 * 64 * 4, stream);
    k_stats<64><<<(NGR + 31) / 32, 64, 0, stream>>>(r2, NGR, 32, sums);
    k_bnfin<64><<<1, 64, 0, stream>>>(sums, bn2g, bn2b, (float)NGR, ss);
    k_apply_relu<64><<<(NGR * 64 + 255) / 256, 256, 0, stream>>>(r2, ss, NGR);

    k_final<<<(NGR + 255) / 256, 256, 0, stream>>>(r2, w3, b3, out);
}

extern "C" void kernel_launch(void* const* d_in, const int* in_sizes, int n_in,
                              void* d_out, int out_size, void* d_ws, size_t ws_size,
                              hipStream_t stream) {
    const int* x        = (const int*)d_in[0];
    const int* esrc     = (const int*)d_in[1];
    const int* edst     = (const int*)d_in[2];
    const int* batch    = (const int*)d_in[3];
    const float* emb    = (const float*)d_in[4];
    const float* basesW = (const float*)d_in[5];
    const float* combW  = (const float*)d_in[6];
    const float* combB  = (const float*)d_in[7];
    const float* convB  = (const float*)d_in[8];
    const float* bnG    = (const float*)d_in[9];
    const float* bnB    = (const float*)d_in[10];
    const float* w1     = (const float*)d_in[11];
    const float* bn1g   = (const float*)d_in[12];
    const float* bn1b   = (const float*)d_in[13];
    const float* w2     = (const float*)d_in[14];
    const float* bn2g   = (const float*)d_in[15];
    const float* bn2b   = (const float*)d_in[16];
    const float* w3     = (const float*)d_in[17];
    const float* b3     = (const float*)d_in[18];
    const int E = in_sizes[1];

    size_t need_full    = carve_need<float, float>(E);
    size_t need_compact = carve_need<bf16, bf16>(E);

    if (ws_size >= need_full) {
        run_all<float, float>(x, esrc, edst, batch, emb, basesW, combW, combB, convB,
                              bnG, bnB, w1, bn1g, bn1b, w2, bn2g, bn2b, w3, b3, E,
                              (float*)d_out, (char*)d_ws, stream);
    } else if (ws_size >= need_compact) {
        run_all<bf16, bf16>(x, esrc, edst, batch, emb, basesW, combW, combB, convB,
                            bnG, bnB, w1, bn1g, bn1b, w2, bn2g, bn2b, w3, b3, E,
                            (float*)d_out, (char*)d_ws, stream);
    } else {
        k_sentinel<<<(out_size + 255) / 256, 256, 0, stream>>>(
            (float*)d_out, out_size, (float)(ws_size >> 20));
    }
}